// Round 10
// baseline (234.684 us; speedup 1.0000x reference)
//
#include <hip/hip_runtime.h>
#include <stdint.h>
#include <stddef.h>

typedef __attribute__((ext_vector_type(4))) float f32x4;
typedef __attribute__((ext_vector_type(4))) uint32_t u32x4;

#define KDIM 4096
#define NH   128
#define MMEM 50000
#define BFEAT 64
#define MLANES 512

// ---- K1: per-column screen thresholds + counter reset -----------------------
// ratsq[j] = ((0.5 - b_j)/||w_j||)^2 ; margin<=0 -> -1 (always flag).
// Screen (K2): row passes iff sumsq*1.0002 < min_j ratsq[j]  =>
// |<m,w_j>| <= ||m||*||w_j|| < 0.5 - b_j for all j  => all code bits 0.
__global__ __launch_bounds__(64) void wnorm_kernel(
    const float* __restrict__ W, const float* __restrict__ hb,
    float* __restrict__ ratsq, int* __restrict__ count) {
  const int j    = blockIdx.x;          // 128 columns
  const int lane = threadIdx.x;
  const f32x4* wv = reinterpret_cast<const f32x4*>(W + (size_t)j * KDIM);
  float s = 0.f;
#pragma unroll
  for (int q = 0; q < 16; ++q) {
    f32x4 v = wv[lane + 64 * q];
    s += v[0] * v[0] + v[1] * v[1] + v[2] * v[2] + v[3] * v[3];
  }
  for (int o = 32; o; o >>= 1) s += __shfl_down(s, o, 64);
  if (lane == 0) {
    float margin = 0.5f - hb[j];
    ratsq[j] = (margin > 0.f) ? (margin * margin / s) : -1.f;
    if (j == 0) *count = 0;
  }
}

// ---- K2: row-norm screen over memory (the 819 MB stream) --------------------
// Wave per row, strided row assignment (simultaneous rows spread over the
// whole array -> all HBM channels active). Passing rows get zero codes;
// failing rows appended to list for the exact fallback.
__global__ __launch_bounds__(512) void rowscreen_kernel(
    const float* __restrict__ A, const float* __restrict__ ratsq,
    int* __restrict__ count, int* __restrict__ list,
    u32x4* __restrict__ hm_bits) {
  __shared__ float rs[NH];
  const int t = threadIdx.x;
  if (t < NH) rs[t] = ratsq[t];
  __syncthreads();
  float minrat = rs[0];
  for (int j = 1; j < NH; ++j) minrat = fminf(minrat, rs[j]);  // LDS broadcast

  const int gw   = blockIdx.x * 8 + (t >> 6);   // global wave id, 2048 waves
  const int lane = t & 63;
  for (int row = gw; row < MMEM; row += 2048) {
    const f32x4* rv = reinterpret_cast<const f32x4*>(A + (size_t)row * KDIM);
    float s0 = 0.f, s1 = 0.f;
#pragma unroll
    for (int q = 0; q < 16; q += 2) {
      f32x4 v0 = rv[lane + 64 * q];
      f32x4 v1 = rv[lane + 64 * (q + 1)];
      s0 += v0[0] * v0[0] + v0[1] * v0[1] + v0[2] * v0[2] + v0[3] * v0[3];
      s1 += v1[0] * v1[0] + v1[1] * v1[1] + v1[2] * v1[2] + v1[3] * v1[3];
    }
    float s = s0 + s1;
    for (int o = 32; o; o >>= 1) s += __shfl_down(s, o, 64);
    if (lane == 0) {
      if (s * 1.0002f < minrat) {
        hm_bits[row] = (u32x4){0u, 0u, 0u, 0u};
      } else {
        int i = atomicAdd(count, 1);
        list[i] = row;
      }
    }
  }
}

// ---- K3: exact f32 fallback for flagged rows (grid-stride; ~0 rows here) ----
__global__ __launch_bounds__(512) void exact_kernel(
    const float* __restrict__ A, const float* __restrict__ W,
    const float* __restrict__ hb, const int* __restrict__ count,
    const int* __restrict__ list, uint32_t* __restrict__ hm_bits) {
  __shared__ unsigned short sb[8];
  const int w    = threadIdx.x >> 6;
  const int lane = threadIdx.x & 63;
  const int cnt  = *count;
  for (int i = blockIdx.x; i < cnt; i += gridDim.x) {
    const int row = list[i];
    const f32x4* rv = reinterpret_cast<const f32x4*>(A + (size_t)row * KDIM);
    unsigned short bits = 0;
    for (int d = 0; d < 16; ++d) {
      const int n = w * 16 + d;
      const f32x4* wv = reinterpret_cast<const f32x4*>(W + (size_t)n * KDIM);
      float s = 0.f;
#pragma unroll 4
      for (int q = 0; q < 16; ++q) {
        f32x4 x = rv[lane + 64 * q], y = wv[lane + 64 * q];
        s += x[0] * y[0] + x[1] * y[1] + x[2] * y[2] + x[3] * y[3];
      }
      for (int o = 32; o; o >>= 1) s += __shfl_down(s, o, 64);
      s = __shfl(s, 0, 64);
      if (s + hb[n] - 0.5f > 0.f) bits |= (unsigned short)(1u << d);
    }
    if (lane == 0) sb[w] = bits;
    __syncthreads();
    if (threadIdx.x < 4) {
      uint32_t word = (uint32_t)sb[2 * threadIdx.x] |
                      ((uint32_t)sb[2 * threadIdx.x + 1] << 16);
      hm_bits[(size_t)row * 4 + threadIdx.x] = word;
    }
    __syncthreads();
  }
}

// ---- K4: inline hf + per-batch argmin Hamming + fused gather (R9, validated)-
__global__ __launch_bounds__(512) void argmin_gather_kernel(
    const uint32_t* __restrict__ hm_bits, const float* __restrict__ feature,
    const float* __restrict__ Wf, const float* __restrict__ hb,
    const float* __restrict__ memory, float* __restrict__ out) {
  __shared__ unsigned char hfb[NH];
  __shared__ uint32_t red[MLANES];
  const int b    = blockIdx.x;
  const int t    = threadIdx.x;
  const int w    = t >> 6;
  const int lane = t & 63;

  // ---- inline hf: 16 f32 dots per wave ----
  const f32x4* fv = reinterpret_cast<const f32x4*>(feature + (size_t)b * KDIM);
#pragma unroll 2
  for (int d = 0; d < 16; ++d) {
    const int n = w * 16 + d;
    const f32x4* wv = reinterpret_cast<const f32x4*>(Wf + (size_t)n * KDIM);
    float s = 0.f;
#pragma unroll 4
    for (int q = 0; q < 16; ++q) {
      f32x4 x = fv[lane + 64 * q], y = wv[lane + 64 * q];
      s += x[0] * y[0] + x[1] * y[1] + x[2] * y[2] + x[3] * y[3];
    }
    for (int o = 32; o; o >>= 1) s += __shfl_down(s, o, 64);
    if (lane == 0) hfb[n] = (s + hb[n] - 0.5f) > 0.f ? 1 : 0;
  }
  __syncthreads();

  uint64_t hf0 = 0, hf1 = 0;
  for (int c = 0; c < 64; ++c) {
    hf0 |= (uint64_t)(hfb[c] & 1u) << c;
    hf1 |= (uint64_t)(hfb[c + 64] & 1u) << c;
  }
  int hfsum = __popcll(hf0) + __popcll(hf1);
  uint32_t best = 0xFFFFFFFFu;
  for (int m = t; m < MMEM; m += MLANES) {
    u32x4 pv = reinterpret_cast<const u32x4*>(hm_bits)[m];
    uint64_t h0 = (uint64_t)pv[0] | ((uint64_t)pv[1] << 32);
    uint64_t h1 = (uint64_t)pv[2] | ((uint64_t)pv[3] << 32);
    int hmsum = __popcll(h0) + __popcll(h1);
    int dot   = __popcll(h0 & hf0) + __popcll(h1 & hf1);
    int hd    = hfsum + hmsum - 2 * dot;
    uint32_t key = ((uint32_t)hd << 16) | (uint32_t)m;   // M < 65536, HD <= 256
    best = best < key ? best : key;
  }
  red[t] = best;
  __syncthreads();
  for (int s = MLANES / 2; s > 0; s >>= 1) {
    if (t < s) red[t] = red[t] < red[t + s] ? red[t] : red[t + s];
    __syncthreads();
  }
  const int m = (int)(red[0] & 0xFFFFu);
  const f32x4* src = reinterpret_cast<const f32x4*>(memory + (size_t)m * KDIM);
  f32x4* dst = reinterpret_cast<f32x4*>(out + (size_t)b * KDIM);
  dst[t]       = src[t];
  dst[t + 512] = src[t + 512];
}

extern "C" void kernel_launch(void* const* d_in, const int* in_sizes, int n_in,
                              void* d_out, int out_size, void* d_ws, size_t ws_size,
                              hipStream_t stream) {
  const float* feature = (const float*)d_in[0];   // [64,64,8,8] == [64,4096]
  const float* memory  = (const float*)d_in[1];   // [50000,4096]
  const float* hash_W  = (const float*)d_in[2];   // [128,4096]
  const float* hash_b  = (const float*)d_in[3];   // [128]
  float* out = (float*)d_out;

  char* ws = (char*)d_ws;
  uint32_t* hm_bits = (uint32_t*)ws;                    //   800,000 B
  float*    ratsq   = (float*)(ws + 800000);            //       512 B
  int*      count   = (int*)(ws + 800512);              //         4 B
  int*      list    = (int*)(ws + 800768);              //   200,000 B

  wnorm_kernel<<<NH, 64, 0, stream>>>(hash_W, hash_b, ratsq, count);
  rowscreen_kernel<<<256, 512, 0, stream>>>(memory, ratsq, count, list,
                                            (u32x4*)hm_bits);
  exact_kernel<<<128, 512, 0, stream>>>(memory, hash_W, hash_b, count, list,
                                        hm_bits);
  argmin_gather_kernel<<<BFEAT, 512, 0, stream>>>(hm_bits, feature, hash_W,
                                                  hash_b, memory, out);
}